// Round 4
// baseline (286.889 us; speedup 1.0000x reference)
//
#include <hip/hip_runtime.h>

// SoftDepthShader: softmax depth blend, N=8 H=256 W=256 K=50 (524288 pixels).
// ~315 MB logical read (~154 MB HBM after L3), ~2 MB write -> memory-bound,
// HBM floor ~25 us; measured VALU work ~29 us -> target ~40-60 us.
//
// R4 design: R3's 8-lane teams + 64 B segments, PLUS software pipelining.
//   R3 stalled at 106 us with VGPR=20: the compiler's max-occupancy scheduler
//   collapsed the 12-load batch to ~8 in flight -> per-wave latency-bound
//   (VALUBusy 27% == 6 waves/SIMD x 60cy issue / ~1500cy stall).
//   Fix: each team processes ITERS=8 pixels; next pixel's 12 loads are issued
//   BEFORE current pixel's compute (rotating register double buffer). The
//   prefetch has no consumer until a full compute phase later, so vmcnt waits
//   are covered by construction. __launch_bounds__(256,4) permits 128 VGPRs
//   so the allocator stops register-minimizing.

constexpr int THREADS = 256;
constexpr int LPP     = 8;               // lanes per pixel (team)
constexpr int TEAMS   = THREADS / LPP;   // 32 teams per block
constexpr int ITERS   = 8;               // pixels per team
constexpr int PPB     = TEAMS * ITERS;   // 256 pixels per block

constexpr float INV_SIGMA  = 1e4f;       // 1/sigma
constexpr float INVG       = 1e4f;       // 1/gamma
constexpr float ZFAR       = 100.0f;
constexpr float ZRANGE     = 99.0f;      // zfar - znear
constexpr float INV_ZRANGE = 1.0f / 99.0f;
constexpr float EPS        = 1e-10f;

struct Raw {
    float2 za, zb, zc, zd;
    float2 da, db, dc, dd;
    int2   fa, fb, fc, fd;
};

__device__ __forceinline__ Raw load_pixel(const float2* __restrict__ z2,
                                          const float2* __restrict__ d2,
                                          const int2*   __restrict__ f2,
                                          size_t pix, int q)
{
    const size_t cb = pix * 25;          // 25 float2 chunks per pixel
    const size_t c0 = cb + q, c1 = cb + q + 8, c2 = cb + q + 16, c3 = cb + 24;
    Raw r;
    r.za = z2[c0]; r.zb = z2[c1]; r.zc = z2[c2]; r.zd = z2[c3];
    r.da = d2[c0]; r.db = d2[c1]; r.dc = d2[c2]; r.dd = d2[c3];
    r.fa = f2[c0]; r.fb = f2[c1]; r.fc = f2[c2]; r.fd = f2[c3];
    return r;
}

__device__ __forceinline__ void process_pixel(const Raw& r, int q,
                                              float* __restrict__ out, size_t pix)
{
    float zv[8], pv[8];
    {
        const bool v3 = (q == 0);        // tail chunk 24 belongs to lane q==0 only
        const bool m0 = (r.fa.x >= 0),       m1 = (r.fa.y >= 0);
        const bool m2 = (r.fb.x >= 0),       m3 = (r.fb.y >= 0);
        const bool m4 = (r.fc.x >= 0),       m5 = (r.fc.y >= 0);
        const bool m6 = v3 && (r.fd.x >= 0), m7 = v3 && (r.fd.y >= 0);
        zv[0] = m0 ? (ZFAR - r.za.x) * INV_ZRANGE : 0.0f;
        zv[1] = m1 ? (ZFAR - r.za.y) * INV_ZRANGE : 0.0f;
        zv[2] = m2 ? (ZFAR - r.zb.x) * INV_ZRANGE : 0.0f;
        zv[3] = m3 ? (ZFAR - r.zb.y) * INV_ZRANGE : 0.0f;
        zv[4] = m4 ? (ZFAR - r.zc.x) * INV_ZRANGE : 0.0f;
        zv[5] = m5 ? (ZFAR - r.zc.y) * INV_ZRANGE : 0.0f;
        zv[6] = m6 ? (ZFAR - r.zd.x) * INV_ZRANGE : 0.0f;
        zv[7] = m7 ? (ZFAR - r.zd.y) * INV_ZRANGE : 0.0f;
        pv[0] = m0 ? 1.0f / (1.0f + __expf(r.da.x * INV_SIGMA)) : 0.0f;
        pv[1] = m1 ? 1.0f / (1.0f + __expf(r.da.y * INV_SIGMA)) : 0.0f;
        pv[2] = m2 ? 1.0f / (1.0f + __expf(r.db.x * INV_SIGMA)) : 0.0f;
        pv[3] = m3 ? 1.0f / (1.0f + __expf(r.db.y * INV_SIGMA)) : 0.0f;
        pv[4] = m4 ? 1.0f / (1.0f + __expf(r.dc.x * INV_SIGMA)) : 0.0f;
        pv[5] = m5 ? 1.0f / (1.0f + __expf(r.dc.y * INV_SIGMA)) : 0.0f;
        pv[6] = m6 ? 1.0f / (1.0f + __expf(r.dd.x * INV_SIGMA)) : 0.0f;
        pv[7] = m7 ? 1.0f / (1.0f + __expf(r.dd.y * INV_SIGMA)) : 0.0f;
    }

    // max over team: local tree + 3-step shuffle within the 8-lane group
    float m = fmaxf(fmaxf(fmaxf(zv[0], zv[1]), fmaxf(zv[2], zv[3])),
                    fmaxf(fmaxf(zv[4], zv[5]), fmaxf(zv[6], zv[7])));
    m = fmaxf(m, __shfl_xor(m, 1));
    m = fmaxf(m, __shfl_xor(m, 2));
    m = fmaxf(m, __shfl_xor(m, 4));
    m = fmaxf(m, EPS);                   // reference: max(max_k z_inv, EPS)

    // weight sums: independent exps, split accumulators
    float S1a = 0.0f, S1b = 0.0f, S2a = 0.0f, S2b = 0.0f;
    #pragma unroll
    for (int j = 0; j < 8; j += 2) {
        const float w0 = pv[j]   * __expf((zv[j]   - m) * INVG);
        const float w1 = pv[j+1] * __expf((zv[j+1] - m) * INVG);
        S1a += w0;
        S1b += w1;
        S2a += w0 * (ZFAR - zv[j]   * ZRANGE);  // reconstruct zbuf; w==0 where masked
        S2b += w1 * (ZFAR - zv[j+1] * ZRANGE);
    }
    float S1 = S1a + S1b;
    float S2 = S2a + S2b;
    S1 += __shfl_xor(S1, 1);  S1 += __shfl_xor(S1, 2);  S1 += __shfl_xor(S1, 4);
    S2 += __shfl_xor(S2, 1);  S2 += __shfl_xor(S2, 2);  S2 += __shfl_xor(S2, 4);

    if (q == 0) {
        const float delta = fmaxf(__expf((EPS - m) * INVG), EPS);
        out[pix] = (S2 + delta) / (S1 + delta);  // BG_BLUE = 1
    }
}

__global__ __launch_bounds__(THREADS, 4) void soft_depth_kernel(
    const float* __restrict__ zbuf,
    const float* __restrict__ dists,
    const int*   __restrict__ p2f,
    float*       __restrict__ out)
{
    const int t    = threadIdx.x;
    const int q    = t & (LPP - 1);
    const int team = t >> 3;
    const size_t base = (size_t)blockIdx.x * PPB + team;

    const float2* __restrict__ z2 = (const float2*)zbuf;
    const float2* __restrict__ d2 = (const float2*)dists;
    const int2*   __restrict__ f2 = (const int2*)p2f;

    // software pipeline: prefetch pixel j+1's 12 loads, then process pixel j
    Raw cur = load_pixel(z2, d2, f2, base, q);
    #pragma unroll
    for (int j = 1; j < ITERS; ++j) {
        Raw nxt = load_pixel(z2, d2, f2, base + (size_t)j * TEAMS, q);
        process_pixel(cur, q, out, base + (size_t)(j - 1) * TEAMS);
        cur = nxt;
    }
    process_pixel(cur, q, out, base + (size_t)(ITERS - 1) * TEAMS);
}

extern "C" void kernel_launch(void* const* d_in, const int* in_sizes, int n_in,
                              void* d_out, int out_size, void* d_ws, size_t ws_size,
                              hipStream_t stream) {
    const float* zbuf  = (const float*)d_in[0];
    const float* dists = (const float*)d_in[1];
    const int*   p2f   = (const int*)d_in[2];
    float* out = (float*)d_out;

    const int pixels = out_size;                 // 524288
    const int blocks = pixels / PPB;             // 2048 (exact)

    soft_depth_kernel<<<dim3(blocks), dim3(THREADS), 0, stream>>>(
        zbuf, dists, p2f, out);
}

// Round 5
// 280.157 us; speedup vs baseline: 1.0240x; 1.0240x over previous
//
#include <hip/hip_runtime.h>

// SoftDepthShader: softmax depth blend, N=8 H=256 W=256 K=50 (524288 pixels).
// ~315 MB logical read (~154 MB HBM after L3), ~2 MB write.
//
// R5 design: R3's 8-lane teams + 64 B segments, with the load batch pinned by
// __builtin_amdgcn_sched_barrier(0).
//   R3 (VGPR=20) and R4's source-level pipeline (VGPR=36) were both defeated
//   by the scheduler's register-minimization: 2-3 loads in flight, ~5-6
//   sequential full-latency vmcnt waits per batch -> per-wave duty ~4.5%
//   (VALUBusy 27% at 6 waves/SIMD). sched_barrier(0) forbids sinking any of
//   the 12 loads past it, forcing all results live across the fence: waits
//   degrade to vmcnt(11), vmcnt(10), ... = ONE memory latency per batch.
//   __launch_bounds__(256,8) targets <=64 VGPR -> 8 waves/SIMD (100% occ).

constexpr int THREADS = 256;
constexpr int LPP     = 8;              // lanes per pixel (team)
constexpr int PPB     = THREADS / LPP;  // 32 pixels per block

constexpr float INV_SIGMA  = 1e4f;      // 1/sigma
constexpr float INVG       = 1e4f;      // 1/gamma
constexpr float ZFAR       = 100.0f;
constexpr float ZRANGE     = 99.0f;     // zfar - znear
constexpr float INV_ZRANGE = 1.0f / 99.0f;
constexpr float EPS        = 1e-10f;

__global__ __launch_bounds__(THREADS, 8) void soft_depth_kernel(
    const float* __restrict__ zbuf,
    const float* __restrict__ dists,
    const int*   __restrict__ p2f,
    float*       __restrict__ out)
{
    const int t = threadIdx.x;
    const int q = t & (LPP - 1);
    const size_t pix = (size_t)blockIdx.x * PPB + (t >> 3);
    const size_t cb  = pix * 25;        // 25 float2 chunks per pixel

    const float2* __restrict__ z2 = (const float2*)zbuf;
    const float2* __restrict__ d2 = (const float2*)dists;
    const int2*   __restrict__ f2 = (const int2*)p2f;

    // ---- load batch: 12 loads, all issued before the fence ----
    const size_t c0 = cb + q, c1 = cb + q + 8, c2 = cb + q + 16, c3 = cb + 24;
    const float2 za = z2[c0], zb = z2[c1], zc = z2[c2];
    const float2 da = d2[c0], db = d2[c1], dc = d2[c2];
    const int2   fa = f2[c0], fb = f2[c1], fc = f2[c2];
    const float2 zd = z2[c3];           // tail chunk 24: 8-lane broadcast, L1-merged
    const float2 dd = d2[c3];
    const int2   fd = f2[c3];

    // Nothing crosses this fence: loads stay above (results pinned live),
    // compute stays below. Kills the scheduler's load-sinking.
    __builtin_amdgcn_sched_barrier(0);

    // ---- transform: masked z_inv and prob = sigmoid(-d/sigma) ----
    float zv[8], pv[8];
    {
        const bool v3 = (q == 0);       // chunk 24 belongs to lane q==0 only
        const bool m0 = (fa.x >= 0),       m1 = (fa.y >= 0);
        const bool m2 = (fb.x >= 0),       m3 = (fb.y >= 0);
        const bool m4 = (fc.x >= 0),       m5 = (fc.y >= 0);
        const bool m6 = v3 && (fd.x >= 0), m7 = v3 && (fd.y >= 0);
        zv[0] = m0 ? (ZFAR - za.x) * INV_ZRANGE : 0.0f;
        zv[1] = m1 ? (ZFAR - za.y) * INV_ZRANGE : 0.0f;
        zv[2] = m2 ? (ZFAR - zb.x) * INV_ZRANGE : 0.0f;
        zv[3] = m3 ? (ZFAR - zb.y) * INV_ZRANGE : 0.0f;
        zv[4] = m4 ? (ZFAR - zc.x) * INV_ZRANGE : 0.0f;
        zv[5] = m5 ? (ZFAR - zc.y) * INV_ZRANGE : 0.0f;
        zv[6] = m6 ? (ZFAR - zd.x) * INV_ZRANGE : 0.0f;
        zv[7] = m7 ? (ZFAR - zd.y) * INV_ZRANGE : 0.0f;
        pv[0] = m0 ? 1.0f / (1.0f + __expf(da.x * INV_SIGMA)) : 0.0f;
        pv[1] = m1 ? 1.0f / (1.0f + __expf(da.y * INV_SIGMA)) : 0.0f;
        pv[2] = m2 ? 1.0f / (1.0f + __expf(db.x * INV_SIGMA)) : 0.0f;
        pv[3] = m3 ? 1.0f / (1.0f + __expf(db.y * INV_SIGMA)) : 0.0f;
        pv[4] = m4 ? 1.0f / (1.0f + __expf(dc.x * INV_SIGMA)) : 0.0f;
        pv[5] = m5 ? 1.0f / (1.0f + __expf(dc.y * INV_SIGMA)) : 0.0f;
        pv[6] = m6 ? 1.0f / (1.0f + __expf(dd.x * INV_SIGMA)) : 0.0f;
        pv[7] = m7 ? 1.0f / (1.0f + __expf(dd.y * INV_SIGMA)) : 0.0f;
    }

    // ---- pass 1: max over team (local tree + 3-step shuffle in 8-lane group) ----
    float m = fmaxf(fmaxf(fmaxf(zv[0], zv[1]), fmaxf(zv[2], zv[3])),
                    fmaxf(fmaxf(zv[4], zv[5]), fmaxf(zv[6], zv[7])));
    m = fmaxf(m, __shfl_xor(m, 1));
    m = fmaxf(m, __shfl_xor(m, 2));
    m = fmaxf(m, __shfl_xor(m, 4));
    m = fmaxf(m, EPS);                  // reference: max(max_k z_inv, EPS)

    // ---- pass 2: weight sums (independent exps, split accumulators) ----
    float S1a = 0.0f, S1b = 0.0f, S2a = 0.0f, S2b = 0.0f;
    #pragma unroll
    for (int j = 0; j < 8; j += 2) {
        const float w0 = pv[j]   * __expf((zv[j]   - m) * INVG);
        const float w1 = pv[j+1] * __expf((zv[j+1] - m) * INVG);
        S1a += w0;
        S1b += w1;
        S2a += w0 * (ZFAR - zv[j]   * ZRANGE);   // reconstruct zbuf; w==0 where masked
        S2b += w1 * (ZFAR - zv[j+1] * ZRANGE);
    }
    float S1 = S1a + S1b;
    float S2 = S2a + S2b;
    S1 += __shfl_xor(S1, 1);  S1 += __shfl_xor(S1, 2);  S1 += __shfl_xor(S1, 4);
    S2 += __shfl_xor(S2, 1);  S2 += __shfl_xor(S2, 2);  S2 += __shfl_xor(S2, 4);

    if (q == 0) {
        const float delta = fmaxf(__expf((EPS - m) * INVG), EPS);
        out[pix] = (S2 + delta) / (S1 + delta);   // BG_BLUE = 1
    }
}

extern "C" void kernel_launch(void* const* d_in, const int* in_sizes, int n_in,
                              void* d_out, int out_size, void* d_ws, size_t ws_size,
                              hipStream_t stream) {
    const float* zbuf  = (const float*)d_in[0];
    const float* dists = (const float*)d_in[1];
    const int*   p2f   = (const int*)d_in[2];
    float* out = (float*)d_out;

    const int pixels = out_size;                 // 524288
    const int blocks = pixels / PPB;             // 16384 (exact)

    soft_depth_kernel<<<dim3(blocks), dim3(THREADS), 0, stream>>>(
        zbuf, dists, p2f, out);
}